// Round 8
// baseline (214.598 us; speedup 1.0000x reference)
//
#include <hip/hip_runtime.h>
#include <math.h>

#define NBULK 62

typedef __attribute__((ext_vector_type(8))) short bf8_t;    // 8 x bf16
typedef __attribute__((ext_vector_type(4))) float f4_t;     // 4 x fp32

#define MFMA16(a, b, c) __builtin_amdgcn_mfma_f32_16x16x32_bf16((a), (b), (c), 0, 0, 0)

__device__ __forceinline__ unsigned short f2bf(float f) {
    unsigned int u = __float_as_uint(f);
    return (unsigned short)((u + 0x7FFFu + ((u >> 16) & 1u)) >> 16);
}
__device__ __forceinline__ float bf2f(unsigned short h) {
    return __uint_as_float(((unsigned int)h) << 16);
}
// pack 2 f32 -> 2 bf16 in one dword (RNE)
__device__ __forceinline__ unsigned cvtpk(float lo, float hi) {
    unsigned r;
    asm("v_cvt_pk_bf16_f32 %0, %1, %2" : "=v"(r) : "v"(lo), "v"(hi));
    return r;
}

// async global->LDS, 16B per lane; lptr must be wave-uniform (HW adds lane*16)
__device__ __forceinline__ void gload16(const void* g, void* l) {
    __builtin_amdgcn_global_load_lds(
        (const __attribute__((address_space(1))) unsigned int*)g,
        (__attribute__((address_space(3))) unsigned int*)l, 16, 0, 0);
}

// ---- ws layout ----
// floats: [0]=psisum [1]=lsf [2]=lsb [3]=spare ; E_fwd @f1024, E_bwd @f6144
// bytes:  NFf (62*16KB) @45056 ; NFb @1060864
#define WS_E_OFF   1024
#define WS_B_OFF   6144
#define WS_NFF_OFF 45056
#define WS_NFB_OFF 1060864

// ===== fragment layout (shared by psi and norm; 16x16x32 MFMA) =====
// perm16(32ks+8q+jj) = 16*(2ks+(jj>>2)) + 4q + (jj&3)   (C-row <-> B-k relabel)
// NFf frag i=(p*4+t)*2+ks, lane l=q*16+ln, halfword jj:
//     M_p[perm16(32ks+8q+jj)][t*16+ln]        (psi A-op; norm-fwd stage1-B & stage2-A)
// NFb frag: M_p[t*16+ln][perm16(32ks+8q+jj)]  (norm-bwd stage1-B & stage2-A)
// Both are 16 chunks x 1KB per site; consumer reads 16B/lane, fully coalesced.
// (verified correct end-to-end in round 5: absmax 0)

extern "C" __global__ __launch_bounds__(256)
void mps_precompute(const float* __restrict__ bulkG,
                    unsigned short* __restrict__ NFfG,
                    unsigned short* __restrict__ NFbG,
                    float* __restrict__ wsF)
{
    __shared__ unsigned short Ff[8192];
    __shared__ unsigned short Fb[8192];
    const int s = blockIdx.x, tid = threadIdx.x;
    if (s == 0 && tid == 0) {   // init accumulators (no memset dispatch)
        wsF[0] = 0.f; wsF[1] = 0.f; wsF[2] = 0.f; wsF[3] = 0.f;
    }
    const float4* src = (const float4*)(bulkG + (size_t)s * 8192);
    for (int c = 0; c < 8; ++c) {
        int idx = tid + c * 256;            // float4 index 0..2047
        float4 v = src[idx];
        int f  = idx * 4;
        int kk = f >> 7;                    // bond-in row 0..63
        int p  = (f >> 6) & 1;
        int j0 = f & 63;                    // bond-out col (multiple of 4)
        float vals[4] = {v.x, v.y, v.z, v.w};
        // NFf: (q,ks,jj) from kk (fixed per float4); (t,ln) from j
        int qf = (kk >> 2) & 3, rf = kk & 3, mf = kk >> 4;
        int ksf = mf >> 1, jjf = (mf & 1) * 4 + rf;
        // NFb: (t,ln) from kk (fixed); (q,ks,jj) from j
        int tb = kk >> 4, lnb = kk & 15;
        #pragma unroll
        for (int t2 = 0; t2 < 4; ++t2) {
            int j = j0 + t2;
            unsigned short b = f2bf(vals[t2]);
            int tf = j >> 4, lnf = j & 15;
            Ff[((p * 4 + tf) * 2 + ksf) * 512 + (qf * 16 + lnf) * 8 + jjf] = b;
            int qb = (j >> 2) & 3, rb = j & 3, mb = j >> 4;
            int ksb = mb >> 1, jjb = (mb & 1) * 4 + rb;
            Fb[((p * 4 + tb) * 2 + ksb) * 512 + (qb * 16 + lnb) * 8 + jjb] = b;
        }
    }
    __syncthreads();
    const uint4* ff4 = (const uint4*)Ff;
    const uint4* fb4 = (const uint4*)Fb;
    uint4* fg = (uint4*)(NFfG + (size_t)s * 8192);
    uint4* bg = (uint4*)(NFbG + (size_t)s * 8192);
    for (int c = 0; c < 4; ++c) {
        int idx = tid + c * 256;
        fg[idx] = ff4[idx];
        bg[idx] = fb4[idx];
    }
}

// coalesced fragment fetch from GLOBAL: 16 x b128, lane-contiguous (psi only)
__device__ __forceinline__ void pfetch(uint4 (&F)[16], const char* tb, int l16)
{
    #pragma unroll
    for (int i = 0; i < 16; ++i)
        F[i] = *(const uint4*)(tb + i * 1024 + l16);
}

// ===== psi helpers: 16-sample in-register chain (zero LDS, zero barriers) =====
__device__ __forceinline__ void pstep(f4_t (&a)[2][4], const uint4 (&F)[16],
                                      const bf8_t (&B)[2])
{
    #pragma unroll
    for (int p = 0; p < 2; ++p)
        #pragma unroll
        for (int mt = 0; mt < 4; ++mt) { f4_t z = {0.f, 0.f, 0.f, 0.f}; a[p][mt] = z; }
    #pragma unroll
    for (int ks = 0; ks < 2; ++ks)
        #pragma unroll
        for (int p = 0; p < 2; ++p)
            #pragma unroll
            for (int mt = 0; mt < 4; ++mt)
                a[p][mt] = MFMA16(*(const bf8_t*)&F[(p * 4 + mt) * 2 + ks], B[ks], a[p][mt]);
}

__device__ __forceinline__ void ppack(bf8_t (&B)[2], const f4_t (&a)[2][4], bool takeB)
{
    #pragma unroll
    for (int ks = 0; ks < 2; ++ks) {
        unsigned w[4];
        #pragma unroll
        for (int d = 0; d < 4; ++d) {
            int mt = 2 * ks + (d >> 1), r = (d & 1) * 2;
            float x0 = takeB ? a[1][mt][r]     : a[0][mt][r];
            float x1 = takeB ? a[1][mt][r + 1] : a[0][mt][r + 1];
            w[d] = cvtpk(x0, x1);
        }
        uint4 u = {w[0], w[1], w[2], w[3]};
        B[ks] = *(const bf8_t*)&u;
    }
}

extern "C" __global__ __launch_bounds__(256, 1)
void mps_main(const int* __restrict__ cfgG, const float* __restrict__ leftG,
              const float* __restrict__ rightG, float* __restrict__ wsF,
              const unsigned short* __restrict__ NFfG,
              const unsigned short* __restrict__ NFbG)
{
    extern __shared__ char smem[];
    const int tid  = threadIdx.x;
    const int bid  = blockIdx.x;
    const int wv   = tid >> 6;
    const int lane = tid & 63;
    const int ln   = lane & 15, q = lane >> 4;
    const int l16  = lane * 16;

    if (bid >= 2) {
        // ===== psi (round-7 verbatim, verified): 64 samples/block = 4 waves x 16;
        //       Fa/Fb double-buffered global-loaded fragments =====
        const char* NF = (const char*)NFfG;
        uint4 Fa[16], Fb[16];
        pfetch(Fa, NF, l16);
        pfetch(Fb, NF + 16384, l16);
        const int s0 = (bid - 2) * 64 + wv * 16;
        // pack sample (=ln) config into 2 dwords via q-partial OR + broadcast
        unsigned part = 0;
        {
            const int4* crow = (const int4*)(cfgG + (size_t)(s0 + ln) * 64 + q * 16);
            #pragma unroll
            for (int c = 0; c < 4; ++c) {
                int4 v = crow[c];
                part |= (unsigned)(v.x & 1) << (c * 4 + 0);
                part |= (unsigned)(v.y & 1) << (c * 4 + 1);
                part |= (unsigned)(v.z & 1) << (c * 4 + 2);
                part |= (unsigned)(v.w & 1) << (c * 4 + 3);
            }
        }
        unsigned pp   = __shfl_xor(part, 16);
        unsigned comb = (q & 1) ? (pp | (part << 16)) : (part | (pp << 16));
        unsigned selLo = __shfl(comb, ln);        // cfg cols 0..31  (from q=0 lane)
        unsigned selHi = __shfl(comb, ln + 32);   // cfg cols 32..63 (from q=2 lane)

        // env0 = left[cfg[:,0]] straight into B-frags (perm16 baked in)
        bf8_t B[2];
        {
            const float* lp = leftG + (selLo & 1u) * 64;
            #pragma unroll
            for (int ks = 0; ks < 2; ++ks) {
                unsigned w[4];
                #pragma unroll
                for (int d = 0; d < 4; ++d) {
                    int k0 = 16 * (2 * ks + (d >> 1)) + 4 * q + 2 * (d & 1);
                    w[d] = (unsigned)f2bf(lp[k0]) | ((unsigned)f2bf(lp[k0 + 1]) << 16);
                }
                uint4 u = {w[0], w[1], w[2], w[3]};
                B[ks] = *(const bf8_t*)&u;
            }
        }
        f4_t a[2][4];
        #define SELBIT(i) ((bool)((((i) < 32) ? (selLo >> (i)) : (selHi >> ((i) - 32))) & 1u))
        for (int t = 0; t < 60; t += 2) {
            pstep(a, Fa, B);
            pfetch(Fa, NF + (size_t)(t + 2) * 16384, l16);   // consumed at t+2
            ppack(B, a, SELBIT(t + 1));
            pstep(a, Fb, B);
            pfetch(Fb, NF + (size_t)(t + 3) * 16384, l16);   // consumed at t+3
            ppack(B, a, SELBIT(t + 2));
        }
        pstep(a, Fa, B);            // site 60
        ppack(B, a, SELBIT(61));
        pstep(a, Fb, B);            // site 61
        {   // final select (cfg col 62) + dot with right[:, cfg col 63]
            bool tb2 = SELBIT(62);
            int selL = (int)(selHi >> 31) & 1;
            float psum = 0.f;
            #pragma unroll
            for (int mt = 0; mt < 4; ++mt)
                #pragma unroll
                for (int r = 0; r < 4; ++r) {
                    float v = tb2 ? a[1][mt][r] : a[0][mt][r];
                    psum = fmaf(v, rightG[(16 * mt + 4 * q + r) * 2 + selL], psum);
                }
            psum += __shfl_xor(psum, 16);   // sum the 4 q-lane partials
            psum += __shfl_xor(psum, 32);
            float lp2 = (lane < 16) ? logf(fmaxf(psum * psum, 1e-12f)) : 0.f;
            #pragma unroll
            for (int o = 1; o < 64; o <<= 1) lp2 += __shfl_xor(lp2, o);
            if (lane == 0) atomicAdd(&wsF[0], lp2);
        }
        #undef SELBIT
    } else {
        // ===== norm chain: register MFMA (round-5-verified math) with LDS-staged
        //       fragment tiles (gload16 double buffer, proven rounds 0-7).
        //       One __syncthreads per site; F regs refreshed per site via ds_read
        //       (same-wave register dependency -> WAR-safe, unlike round-6's
        //       async global reload into live MFMA sources). =====
        unsigned short* Ms0 = (unsigned short*)smem;     // 8192 (frag tile)
        unsigned short* Ms1 = Ms0 + 8192;                // 8192
        unsigned short* XsS = Ms1 + 8192;                // [2][4][2][512] = 8192
        float* wredS = (float*)(XsS + 8192);             // [2][4]

        const bool fwd = (bid == 0);
        const char* NF = fwd ? (const char*)NFfG : (const char*)NFbG;
        {   // prefetch site 0 tile into Ms0
            int st = fwd ? 0 : 61;
            const char* g = NF + (size_t)st * 16384;
            for (int c = 0; c < 4; ++c) {
                int chunk = wv * 4 + c;
                gload16(g + chunk * 1024 + (size_t)lane * 16, (char*)Ms0 + chunk * 1024);
            }
        }
        // E0 A1-frags in-register: E0 = L^T L (fwd) / R R^T (bwd)  [round-5 verbatim]
        bf8_t A1[4][2];
        {
            float li0[4], li1[4];
            #pragma unroll
            for (int mt = 0; mt < 4; ++mt) {
                int m = mt * 16 + ln;
                li0[mt] = fwd ? leftG[m]      : rightG[m * 2];
                li1[mt] = fwd ? leftG[64 + m] : rightG[m * 2 + 1];
            }
            #pragma unroll
            for (int ks = 0; ks < 2; ++ks) {
                float k0v[8], k1v[8];
                #pragma unroll
                for (int jj = 0; jj < 8; ++jj) {
                    int K = 16 * (2 * ks + (jj >> 2)) + 4 * q + (jj & 3);
                    k0v[jj] = fwd ? leftG[K]      : rightG[K * 2];
                    k1v[jj] = fwd ? leftG[64 + K] : rightG[K * 2 + 1];
                }
                #pragma unroll
                for (int mt = 0; mt < 4; ++mt) {
                    unsigned w[4];
                    #pragma unroll
                    for (int d = 0; d < 4; ++d) {
                        float x0 = li0[mt] * k0v[2 * d]     + li1[mt] * k1v[2 * d];
                        float x1 = li0[mt] * k0v[2 * d + 1] + li1[mt] * k1v[2 * d + 1];
                        w[d] = cvtpk(x0, x1);
                    }
                    uint4 u = {w[0], w[1], w[2], w[3]};
                    A1[mt][ks] = *(const bf8_t*)&u;
                }
            }
        }
        float lsum = 0.f;
        f4_t acc2[4];
        for (int k = 0; k < 31; ++k) {
            __syncthreads();   // Ms[k&1] gloads drained; Xs[k&1], wred[(k-1)&1] visible
            if (k > 0) {       // reload A1 from exchange written at site k-1
                #pragma unroll
                for (int mt = 0; mt < 4; ++mt)
                    #pragma unroll
                    for (int ks = 0; ks < 2; ++ks)
                        A1[mt][ks] = *(const bf8_t*)&XsS[((k & 1) * 8 + mt * 2 + ks) * 512
                                                         + lane * 8];
            }
            // fragments for this site: 16 x ds_read_b128, conflict-free
            const unsigned short* Msrc = (k & 1) ? Ms1 : Ms0;
            uint4 F[16];
            #pragma unroll
            for (int i = 0; i < 16; ++i)
                F[i] = *(const uint4*)(Msrc + i * 512 + lane * 8);
            // prefetch next site tile into the other Ms (full site of slack)
            if (k + 1 < 31) {
                int sn = fwd ? (k + 1) : (61 - (k + 1));
                const char* g = NF + (size_t)sn * 16384;
                char* l = (char*)((k & 1) ? Ms0 : Ms1);
                for (int c = 0; c < 4; ++c) {
                    int chunk = wv * 4 + c;
                    gload16(g + chunk * 1024 + (size_t)lane * 16, l + chunk * 1024);
                }
            }
            float inv = 1.f;
            if (k > 0) {
                const float* wp = wredS + ((k - 1) & 1) * 4;
                float mm = fmaxf(fmaxf(wp[0], wp[1]), fmaxf(wp[2], wp[3]));
                float sc = fmaxf(mm, 1e-30f);
                inv = 1.f / sc;
                lsum += logf(sc);
            }
            #pragma unroll
            for (int mt = 0; mt < 4; ++mt) { f4_t z = {0.f, 0.f, 0.f, 0.f}; acc2[mt] = z; }
            #pragma unroll
            for (int p = 0; p < 2; ++p) {
                // stage1: S_p[:, own cols] = E * M_p   (A = E-frags, B = F[(p,wv,ks)])
                f4_t acc1[4];
                #pragma unroll
                for (int mt = 0; mt < 4; ++mt) { f4_t z = {0.f, 0.f, 0.f, 0.f}; acc1[mt] = z; }
                #pragma unroll
                for (int ks = 0; ks < 2; ++ks)
                    #pragma unroll
                    for (int mt = 0; mt < 4; ++mt)
                        acc1[mt] = MFMA16(A1[mt][ks], *(const bf8_t*)&F[(p * 4 + wv) * 2 + ks],
                                          acc1[mt]);
                // lane-local perm pack: acc1 (C layout) -> B2 (B-operand k-slots)
                bf8_t B2[2];
                #pragma unroll
                for (int ks = 0; ks < 2; ++ks) {
                    unsigned w[4];
                    #pragma unroll
                    for (int d = 0; d < 4; ++d) {
                        int mt = 2 * ks + (d >> 1), r = (d & 1) * 2;
                        w[d] = cvtpk(acc1[mt][r], acc1[mt][r + 1]);
                    }
                    uint4 u = {w[0], w[1], w[2], w[3]};
                    B2[ks] = *(const bf8_t*)&u;
                }
                // stage2: E'[:, own cols] += M_p-side * S_p  (A = F[(p,mt,ks)])
                #pragma unroll
                for (int ks = 0; ks < 2; ++ks)
                    #pragma unroll
                    for (int mt = 0; mt < 4; ++mt)
                        acc2[mt] = MFMA16(*(const bf8_t*)&F[(p * 4 + mt) * 2 + ks], B2[ks],
                                          acc2[mt]);
            }
            // deferred rescale (prev-site max) + this-site max
            float mx = 0.f;
            #pragma unroll
            for (int mt = 0; mt < 4; ++mt)
                #pragma unroll
                for (int r = 0; r < 4; ++r) {
                    float x = acc2[mt][r] * inv;
                    acc2[mt][r] = x;
                    mx = fmaxf(mx, fabsf(x));
                }
            // pack own A1'-frags for next site (E' symmetric -> lane-local), exchange
            #pragma unroll
            for (int ks = 0; ks < 2; ++ks) {
                unsigned w[4];
                #pragma unroll
                for (int d = 0; d < 4; ++d) {
                    int mt = 2 * ks + (d >> 1), r = (d & 1) * 2;
                    w[d] = cvtpk(acc2[mt][r], acc2[mt][r + 1]);
                }
                uint4 u = {w[0], w[1], w[2], w[3]};
                *(uint4*)&XsS[(((k + 1) & 1) * 8 + wv * 2 + ks) * 512 + lane * 8] = u;
            }
            #pragma unroll
            for (int o = 32; o > 0; o >>= 1) mx = fmaxf(mx, __shfl_xor(mx, o));
            if (lane == 0) wredS[(k & 1) * 4 + wv] = mx;
        }
        // write E (f32) for finalize  [round-5 verbatim]
        float* dst = wsF + (fwd ? WS_E_OFF : WS_B_OFF);
        #pragma unroll
        for (int mt = 0; mt < 4; ++mt)
            #pragma unroll
            for (int r = 0; r < 4; ++r)
                dst[(16 * mt + 4 * q + r) * 64 + wv * 16 + ln] = acc2[mt][r];
        if (tid == 0) wsF[fwd ? 1 : 2] = lsum;
    }
}

extern "C" __global__ void mps_finalize(const float* __restrict__ wsF, float* __restrict__ out)
{
    const int lane = threadIdx.x;  // 64 threads
    const float* E  = wsF + WS_E_OFF;
    const float* Bm = wsF + WS_B_OFF;
    float a = 0.f;
    #pragma unroll 8
    for (int j = 0; j < 64; ++j)
        a = fmaf(E[j * 64 + lane], Bm[j * 64 + lane], a);   // coalesced
    #pragma unroll
    for (int off = 32; off > 0; off >>= 1)
        a += __shfl_down(a, off);
    if (lane == 0) {
        const float z = fmaxf(a, 1e-30f);
        const float log_z = logf(z) + wsF[1] + wsF[2];
        out[0] = log_z - wsF[0] * (1.0f / 8192.0f);
    }
}

extern "C" void kernel_launch(void* const* d_in, const int* in_sizes, int n_in,
                              void* d_out, int out_size, void* d_ws, size_t ws_size,
                              hipStream_t stream)
{
    const int*   cfg   = (const int*)d_in[0];    // (8192, 64) int32
    const float* left  = (const float*)d_in[1];  // (2, 64)
    const float* bulk  = (const float*)d_in[2];  // (62, 64, 2, 64)
    const float* right = (const float*)d_in[3];  // (64, 2)
    float* wsF = (float*)d_ws;
    unsigned short* NFf = (unsigned short*)((char*)d_ws + WS_NFF_OFF);
    unsigned short* NFb = (unsigned short*)((char*)d_ws + WS_NFB_OFF);

    mps_precompute<<<dim3(62), dim3(256), 0, stream>>>(bulk, NFf, NFb, wsF);
    // blocks 0,1 = norm chains (register MFMA + LDS-staged frags);
    // 2..129 = psi (64 samples each: 4 waves x 16-sample in-register chains)
    mps_main<<<dim3(130), dim3(256), 49216, stream>>>(cfg, left, right, wsF, NFf, NFb);
    mps_finalize<<<dim3(1), dim3(64), 0, stream>>>(wsF, (float*)d_out);
}

// Round 9
// 104.679 us; speedup vs baseline: 2.0501x; 2.0501x over previous
//
#include <hip/hip_runtime.h>
#include <math.h>

#define NBULK 62

typedef __attribute__((ext_vector_type(8))) short bf8_t;    // 8 x bf16
typedef __attribute__((ext_vector_type(4))) float f4_t;     // 4 x fp32

#define MFMA16(a, b, c) __builtin_amdgcn_mfma_f32_16x16x32_bf16((a), (b), (c), 0, 0, 0)

__device__ __forceinline__ unsigned short f2bf(float f) {
    unsigned int u = __float_as_uint(f);
    return (unsigned short)((u + 0x7FFFu + ((u >> 16) & 1u)) >> 16);
}
__device__ __forceinline__ float bf2f(unsigned short h) {
    return __uint_as_float(((unsigned int)h) << 16);
}
// pack 2 f32 -> 2 bf16 in one dword (RNE)
__device__ __forceinline__ unsigned cvtpk(float lo, float hi) {
    unsigned r;
    asm("v_cvt_pk_bf16_f32 %0, %1, %2" : "=v"(r) : "v"(lo), "v"(hi));
    return r;
}

// async global->LDS, 16B per lane; lptr must be wave-uniform (HW adds lane*16)
__device__ __forceinline__ void gload16(const void* g, void* l) {
    __builtin_amdgcn_global_load_lds(
        (const __attribute__((address_space(1))) unsigned int*)g,
        (__attribute__((address_space(3))) unsigned int*)l, 16, 0, 0);
}

// ---- ws layout ----
// floats: [0]=psisum [1]=lsf [2]=lsb [3]=spare ; E_fwd @f1024, E_bwd @f6144
// bytes:  NFf (62*16KB) @45056 ; NFb @1060864
#define WS_E_OFF   1024
#define WS_B_OFF   6144
#define WS_NFF_OFF 45056
#define WS_NFB_OFF 1060864

// ===== fragment layout (shared by psi and norm; 16x16x32 MFMA) =====
// perm16(32ks+8q+jj) = 16*(2ks+(jj>>2)) + 4q + (jj&3)   (C-row <-> B-k relabel)
// NFf frag i=(p*4+t)*2+ks, lane l=q*16+ln, halfword jj:
//     M_p[perm16(32ks+8q+jj)][t*16+ln]        (psi A-op; norm-fwd stage1-B & stage2-A)
// NFb frag: M_p[t*16+ln][perm16(32ks+8q+jj)]  (norm-bwd stage1-B & stage2-A)
// Both are 16 chunks x 1KB per site; consumer reads 16B/lane, fully coalesced.
// (verified correct end-to-end in round 5/7/8: absmax 0)

extern "C" __global__ __launch_bounds__(256)
void mps_precompute(const float* __restrict__ bulkG,
                    unsigned short* __restrict__ NFfG,
                    unsigned short* __restrict__ NFbG,
                    float* __restrict__ wsF)
{
    __shared__ unsigned short Ff[8192];
    __shared__ unsigned short Fb[8192];
    const int s = blockIdx.x, tid = threadIdx.x;
    if (s == 0 && tid == 0) {   // init accumulators (no memset dispatch)
        wsF[0] = 0.f; wsF[1] = 0.f; wsF[2] = 0.f; wsF[3] = 0.f;
    }
    const float4* src = (const float4*)(bulkG + (size_t)s * 8192);
    for (int c = 0; c < 8; ++c) {
        int idx = tid + c * 256;            // float4 index 0..2047
        float4 v = src[idx];
        int f  = idx * 4;
        int kk = f >> 7;                    // bond-in row 0..63
        int p  = (f >> 6) & 1;
        int j0 = f & 63;                    // bond-out col (multiple of 4)
        float vals[4] = {v.x, v.y, v.z, v.w};
        // NFf: (q,ks,jj) from kk (fixed per float4); (t,ln) from j
        int qf = (kk >> 2) & 3, rf = kk & 3, mf = kk >> 4;
        int ksf = mf >> 1, jjf = (mf & 1) * 4 + rf;
        // NFb: (t,ln) from kk (fixed); (q,ks,jj) from j
        int tb = kk >> 4, lnb = kk & 15;
        #pragma unroll
        for (int t2 = 0; t2 < 4; ++t2) {
            int j = j0 + t2;
            unsigned short b = f2bf(vals[t2]);
            int tf = j >> 4, lnf = j & 15;
            Ff[((p * 4 + tf) * 2 + ksf) * 512 + (qf * 16 + lnf) * 8 + jjf] = b;
            int qb = (j >> 2) & 3, rb = j & 3, mb = j >> 4;
            int ksb = mb >> 1, jjb = (mb & 1) * 4 + rb;
            Fb[((p * 4 + tb) * 2 + ksb) * 512 + (qb * 16 + lnb) * 8 + jjb] = b;
        }
    }
    __syncthreads();
    const uint4* ff4 = (const uint4*)Ff;
    const uint4* fb4 = (const uint4*)Fb;
    uint4* fg = (uint4*)(NFfG + (size_t)s * 8192);
    uint4* bg = (uint4*)(NFbG + (size_t)s * 8192);
    for (int c = 0; c < 4; ++c) {
        int idx = tid + c * 256;
        fg[idx] = ff4[idx];
        bg[idx] = fb4[idx];
    }
}

// coalesced fragment fetch from GLOBAL: 16 x b128, lane-contiguous (psi only)
__device__ __forceinline__ void pfetch(uint4 (&F)[16], const char* tb, int l16)
{
    #pragma unroll
    for (int i = 0; i < 16; ++i)
        F[i] = *(const uint4*)(tb + i * 1024 + l16);
}

// ===== psi helpers: 16-sample in-register chain (zero LDS, zero barriers) =====
__device__ __forceinline__ void pstep(f4_t (&a)[2][4], const uint4 (&F)[16],
                                      const bf8_t (&B)[2])
{
    #pragma unroll
    for (int p = 0; p < 2; ++p)
        #pragma unroll
        for (int mt = 0; mt < 4; ++mt) { f4_t z = {0.f, 0.f, 0.f, 0.f}; a[p][mt] = z; }
    #pragma unroll
    for (int ks = 0; ks < 2; ++ks)
        #pragma unroll
        for (int p = 0; p < 2; ++p)
            #pragma unroll
            for (int mt = 0; mt < 4; ++mt)
                a[p][mt] = MFMA16(*(const bf8_t*)&F[(p * 4 + mt) * 2 + ks], B[ks], a[p][mt]);
}

__device__ __forceinline__ void ppack(bf8_t (&B)[2], const f4_t (&a)[2][4], bool takeB)
{
    #pragma unroll
    for (int ks = 0; ks < 2; ++ks) {
        unsigned w[4];
        #pragma unroll
        for (int d = 0; d < 4; ++d) {
            int mt = 2 * ks + (d >> 1), r = (d & 1) * 2;
            float x0 = takeB ? a[1][mt][r]     : a[0][mt][r];
            float x1 = takeB ? a[1][mt][r + 1] : a[0][mt][r + 1];
            w[d] = cvtpk(x0, x1);
        }
        uint4 u = {w[0], w[1], w[2], w[3]};
        B[ks] = *(const bf8_t*)&u;
    }
}

extern "C" __global__ __launch_bounds__(256, 1)
void mps_main(const int* __restrict__ cfgG, const float* __restrict__ leftG,
              const float* __restrict__ rightG, float* __restrict__ wsF,
              const unsigned short* __restrict__ NFfG,
              const unsigned short* __restrict__ NFbG)
{
    extern __shared__ char smem[];
    const int tid  = threadIdx.x;
    const int bid  = blockIdx.x;
    const int wv   = tid >> 6;
    const int lane = tid & 63;
    const int ln   = lane & 15, q = lane >> 4;
    const int l16  = lane * 16;

    if (bid >= 2) {
        // ===== psi: 64 samples/block = 4 waves x 16; Fa/Fb double buffer.
        //       sched_barrier(0) after each pfetch PINS the loads 2 sites ahead
        //       (rounds 7/8: scheduler sank them to just-before-use, VGPR=104,
        //        exposing ~800cy L2 latency per site). =====
        const char* NF = (const char*)NFfG;
        uint4 Fa[16], Fb[16];
        pfetch(Fa, NF, l16);
        pfetch(Fb, NF + 16384, l16);
        const int s0 = (bid - 2) * 64 + wv * 16;
        // pack sample (=ln) config into 2 dwords via q-partial OR + broadcast
        unsigned part = 0;
        {
            const int4* crow = (const int4*)(cfgG + (size_t)(s0 + ln) * 64 + q * 16);
            #pragma unroll
            for (int c = 0; c < 4; ++c) {
                int4 v = crow[c];
                part |= (unsigned)(v.x & 1) << (c * 4 + 0);
                part |= (unsigned)(v.y & 1) << (c * 4 + 1);
                part |= (unsigned)(v.z & 1) << (c * 4 + 2);
                part |= (unsigned)(v.w & 1) << (c * 4 + 3);
            }
        }
        unsigned pp   = __shfl_xor(part, 16);
        unsigned comb = (q & 1) ? (pp | (part << 16)) : (part | (pp << 16));
        unsigned selLo = __shfl(comb, ln);        // cfg cols 0..31  (from q=0 lane)
        unsigned selHi = __shfl(comb, ln + 32);   // cfg cols 32..63 (from q=2 lane)

        // env0 = left[cfg[:,0]] straight into B-frags (perm16 baked in)
        bf8_t B[2];
        {
            const float* lp = leftG + (selLo & 1u) * 64;
            #pragma unroll
            for (int ks = 0; ks < 2; ++ks) {
                unsigned w[4];
                #pragma unroll
                for (int d = 0; d < 4; ++d) {
                    int k0 = 16 * (2 * ks + (d >> 1)) + 4 * q + 2 * (d & 1);
                    w[d] = (unsigned)f2bf(lp[k0]) | ((unsigned)f2bf(lp[k0 + 1]) << 16);
                }
                uint4 u = {w[0], w[1], w[2], w[3]};
                B[ks] = *(const bf8_t*)&u;
            }
        }
        f4_t a[2][4];
        #define SELBIT(i) ((bool)((((i) < 32) ? (selLo >> (i)) : (selHi >> ((i) - 32))) & 1u))
        for (int t = 0; t < 60; t += 2) {
            pstep(a, Fa, B);
            pfetch(Fa, NF + (size_t)(t + 2) * 16384, l16);   // consumed at t+2
            __builtin_amdgcn_sched_barrier(0);               // pin: no sinking
            ppack(B, a, SELBIT(t + 1));
            pstep(a, Fb, B);
            pfetch(Fb, NF + (size_t)(t + 3) * 16384, l16);   // consumed at t+3
            __builtin_amdgcn_sched_barrier(0);               // pin: no sinking
            ppack(B, a, SELBIT(t + 2));
        }
        pstep(a, Fa, B);            // site 60
        ppack(B, a, SELBIT(61));
        pstep(a, Fb, B);            // site 61
        {   // final select (cfg col 62) + dot with right[:, cfg col 63]
            bool tb2 = SELBIT(62);
            int selL = (int)(selHi >> 31) & 1;
            float psum = 0.f;
            #pragma unroll
            for (int mt = 0; mt < 4; ++mt)
                #pragma unroll
                for (int r = 0; r < 4; ++r) {
                    float v = tb2 ? a[1][mt][r] : a[0][mt][r];
                    psum = fmaf(v, rightG[(16 * mt + 4 * q + r) * 2 + selL], psum);
                }
            psum += __shfl_xor(psum, 16);   // sum the 4 q-lane partials
            psum += __shfl_xor(psum, 32);
            float lp2 = (lane < 16) ? logf(fmaxf(psum * psum, 1e-12f)) : 0.f;
            #pragma unroll
            for (int o = 1; o < 64; o <<= 1) lp2 += __shfl_xor(lp2, o);
            if (lane == 0) atomicAdd(&wsF[0], lp2);
        }
        #undef SELBIT
    } else {
        // ===== norm chain: register MFMA + LDS-staged tiles (round-8 structure)
        //       FIX (rule #20): stage1's wv-dependent B-frags are now loaded via
        //       runtime LDS ADDRESS into statically-indexed regs (B1f); round 8's
        //       F[(p*4+wv)*2+ks] runtime REGISTER index put all of F in scratch
        //       (WRITE_SIZE 48->176KB, 157us). All F indices below are static. =====
        unsigned short* Ms0 = (unsigned short*)smem;     // 8192 (frag tile)
        unsigned short* Ms1 = Ms0 + 8192;                // 8192
        unsigned short* XsS = Ms1 + 8192;                // [2][4][2][512] = 8192
        float* wredS = (float*)(XsS + 8192);             // [2][4]

        const bool fwd = (bid == 0);
        const char* NF = fwd ? (const char*)NFfG : (const char*)NFbG;
        {   // prefetch site 0 tile into Ms0
            int st = fwd ? 0 : 61;
            const char* g = NF + (size_t)st * 16384;
            for (int c = 0; c < 4; ++c) {
                int chunk = wv * 4 + c;
                gload16(g + chunk * 1024 + (size_t)lane * 16, (char*)Ms0 + chunk * 1024);
            }
        }
        // E0 A1-frags in-register: E0 = L^T L (fwd) / R R^T (bwd)  [round-5 verbatim]
        bf8_t A1[4][2];
        {
            float li0[4], li1[4];
            #pragma unroll
            for (int mt = 0; mt < 4; ++mt) {
                int m = mt * 16 + ln;
                li0[mt] = fwd ? leftG[m]      : rightG[m * 2];
                li1[mt] = fwd ? leftG[64 + m] : rightG[m * 2 + 1];
            }
            #pragma unroll
            for (int ks = 0; ks < 2; ++ks) {
                float k0v[8], k1v[8];
                #pragma unroll
                for (int jj = 0; jj < 8; ++jj) {
                    int K = 16 * (2 * ks + (jj >> 2)) + 4 * q + (jj & 3);
                    k0v[jj] = fwd ? leftG[K]      : rightG[K * 2];
                    k1v[jj] = fwd ? leftG[64 + K] : rightG[K * 2 + 1];
                }
                #pragma unroll
                for (int mt = 0; mt < 4; ++mt) {
                    unsigned w[4];
                    #pragma unroll
                    for (int d = 0; d < 4; ++d) {
                        float x0 = li0[mt] * k0v[2 * d]     + li1[mt] * k1v[2 * d];
                        float x1 = li0[mt] * k0v[2 * d + 1] + li1[mt] * k1v[2 * d + 1];
                        w[d] = cvtpk(x0, x1);
                    }
                    uint4 u = {w[0], w[1], w[2], w[3]};
                    A1[mt][ks] = *(const bf8_t*)&u;
                }
            }
        }
        float lsum = 0.f;
        f4_t acc2[4];
        for (int k = 0; k < 31; ++k) {
            __syncthreads();   // Ms[k&1] gloads drained; Xs[k&1], wred[(k-1)&1] visible
            if (k > 0) {       // reload A1 from exchange written at site k-1 (LDS addr)
                #pragma unroll
                for (int mt = 0; mt < 4; ++mt)
                    #pragma unroll
                    for (int ks = 0; ks < 2; ++ks)
                        A1[mt][ks] = *(const bf8_t*)&XsS[((k & 1) * 8 + mt * 2 + ks) * 512
                                                         + lane * 8];
            }
            const unsigned short* Msrc = (k & 1) ? Ms1 : Ms0;
            // stage2-A fragments: 16 x ds_read_b128, ALL STATIC register indices
            uint4 F[16];
            #pragma unroll
            for (int i = 0; i < 16; ++i)
                F[i] = *(const uint4*)(Msrc + i * 512 + lane * 8);
            // stage1-B fragments: wv enters the LDS ADDRESS (legal), not a reg index
            bf8_t B1f[2][2];
            #pragma unroll
            for (int p = 0; p < 2; ++p)
                #pragma unroll
                for (int ks = 0; ks < 2; ++ks)
                    B1f[p][ks] = *(const bf8_t*)(Msrc + ((p * 4 + wv) * 2 + ks) * 512
                                                 + lane * 8);
            // prefetch next site tile into the other Ms (full site of slack)
            if (k + 1 < 31) {
                int sn = fwd ? (k + 1) : (61 - (k + 1));
                const char* g = NF + (size_t)sn * 16384;
                char* l = (char*)((k & 1) ? Ms0 : Ms1);
                for (int c = 0; c < 4; ++c) {
                    int chunk = wv * 4 + c;
                    gload16(g + chunk * 1024 + (size_t)lane * 16, l + chunk * 1024);
                }
            }
            float inv = 1.f;
            if (k > 0) {
                const float* wp = wredS + ((k - 1) & 1) * 4;
                float mm = fmaxf(fmaxf(wp[0], wp[1]), fmaxf(wp[2], wp[3]));
                float sc = fmaxf(mm, 1e-30f);
                inv = 1.f / sc;
                lsum += logf(sc);
            }
            #pragma unroll
            for (int mt = 0; mt < 4; ++mt) { f4_t z = {0.f, 0.f, 0.f, 0.f}; acc2[mt] = z; }
            #pragma unroll
            for (int p = 0; p < 2; ++p) {
                // stage1: S_p[:, own cols] = E * M_p   (A = E-frags, B = B1f[p][ks])
                f4_t acc1[4];
                #pragma unroll
                for (int mt = 0; mt < 4; ++mt) { f4_t z = {0.f, 0.f, 0.f, 0.f}; acc1[mt] = z; }
                #pragma unroll
                for (int ks = 0; ks < 2; ++ks)
                    #pragma unroll
                    for (int mt = 0; mt < 4; ++mt)
                        acc1[mt] = MFMA16(A1[mt][ks], B1f[p][ks], acc1[mt]);
                // lane-local perm pack: acc1 (C layout) -> B2 (B-operand k-slots)
                bf8_t B2[2];
                #pragma unroll
                for (int ks = 0; ks < 2; ++ks) {
                    unsigned w[4];
                    #pragma unroll
                    for (int d = 0; d < 4; ++d) {
                        int mt = 2 * ks + (d >> 1), r = (d & 1) * 2;
                        w[d] = cvtpk(acc1[mt][r], acc1[mt][r + 1]);
                    }
                    uint4 u = {w[0], w[1], w[2], w[3]};
                    B2[ks] = *(const bf8_t*)&u;
                }
                // stage2: E'[:, own cols] += M_p-side * S_p  (A = F[static indices])
                #pragma unroll
                for (int ks = 0; ks < 2; ++ks)
                    #pragma unroll
                    for (int mt = 0; mt < 4; ++mt)
                        acc2[mt] = MFMA16(*(const bf8_t*)&F[(p * 4 + mt) * 2 + ks], B2[ks],
                                          acc2[mt]);
            }
            // deferred rescale (prev-site max) + this-site max
            float mx = 0.f;
            #pragma unroll
            for (int mt = 0; mt < 4; ++mt)
                #pragma unroll
                for (int r = 0; r < 4; ++r) {
                    float x = acc2[mt][r] * inv;
                    acc2[mt][r] = x;
                    mx = fmaxf(mx, fabsf(x));
                }
            // pack own A1'-frags for next site (E' symmetric -> lane-local), exchange
            #pragma unroll
            for (int ks = 0; ks < 2; ++ks) {
                unsigned w[4];
                #pragma unroll
                for (int d = 0; d < 4; ++d) {
                    int mt = 2 * ks + (d >> 1), r = (d & 1) * 2;
                    w[d] = cvtpk(acc2[mt][r], acc2[mt][r + 1]);
                }
                uint4 u = {w[0], w[1], w[2], w[3]};
                *(uint4*)&XsS[(((k + 1) & 1) * 8 + wv * 2 + ks) * 512 + lane * 8] = u;
            }
            #pragma unroll
            for (int o = 32; o > 0; o >>= 1) mx = fmaxf(mx, __shfl_xor(mx, o));
            if (lane == 0) wredS[(k & 1) * 4 + wv] = mx;
        }
        // write E (f32) for finalize  [round-5 verbatim]
        float* dst = wsF + (fwd ? WS_E_OFF : WS_B_OFF);
        #pragma unroll
        for (int mt = 0; mt < 4; ++mt)
            #pragma unroll
            for (int r = 0; r < 4; ++r)
                dst[(16 * mt + 4 * q + r) * 64 + wv * 16 + ln] = acc2[mt][r];
        if (tid == 0) wsF[fwd ? 1 : 2] = lsum;
    }
}

extern "C" __global__ void mps_finalize(const float* __restrict__ wsF, float* __restrict__ out)
{
    const int lane = threadIdx.x;  // 64 threads
    const float* E  = wsF + WS_E_OFF;
    const float* Bm = wsF + WS_B_OFF;
    float a = 0.f;
    #pragma unroll 8
    for (int j = 0; j < 64; ++j)
        a = fmaf(E[j * 64 + lane], Bm[j * 64 + lane], a);   // coalesced
    #pragma unroll
    for (int off = 32; off > 0; off >>= 1)
        a += __shfl_down(a, off);
    if (lane == 0) {
        const float z = fmaxf(a, 1e-30f);
        const float log_z = logf(z) + wsF[1] + wsF[2];
        out[0] = log_z - wsF[0] * (1.0f / 8192.0f);
    }
}

extern "C" void kernel_launch(void* const* d_in, const int* in_sizes, int n_in,
                              void* d_out, int out_size, void* d_ws, size_t ws_size,
                              hipStream_t stream)
{
    const int*   cfg   = (const int*)d_in[0];    // (8192, 64) int32
    const float* left  = (const float*)d_in[1];  // (2, 64)
    const float* bulk  = (const float*)d_in[2];  // (62, 64, 2, 64)
    const float* right = (const float*)d_in[3];  // (64, 2)
    float* wsF = (float*)d_ws;
    unsigned short* NFf = (unsigned short*)((char*)d_ws + WS_NFF_OFF);
    unsigned short* NFb = (unsigned short*)((char*)d_ws + WS_NFB_OFF);

    mps_precompute<<<dim3(62), dim3(256), 0, stream>>>(bulk, NFf, NFb, wsF);
    // blocks 0,1 = norm chains (register MFMA + LDS-staged frags, static reg idx);
    // 2..129 = psi (64 samples each: 4 waves x 16-sample in-register chains)
    mps_main<<<dim3(130), dim3(256), 49216, stream>>>(cfg, left, right, wsF, NFf, NFb);
    mps_finalize<<<dim3(1), dim3(64), 0, stream>>>(wsF, (float*)d_out);
}